// Round 4
// baseline (307.598 us; speedup 1.0000x reference)
//
#include <hip/hip_runtime.h>

// Problem constants
#define BB 262144   // batch rows
// d_out layout: action [B,6] @0, latent_vf [B,128] @6B, expout [B,12] @134B

typedef float fx4 __attribute__((ext_vector_type(4)));
typedef float fx2 __attribute__((ext_vector_type(2)));
typedef short sx8 __attribute__((ext_vector_type(8)));     // 8 bf16 in 4 VGPRs
typedef unsigned ux4 __attribute__((ext_vector_type(4)));

#if __has_builtin(__builtin_amdgcn_wave_barrier)
#define WB() __builtin_amdgcn_wave_barrier()
#else
#define WB()
#endif

// Packed bf16 B-fragment weight table in module-owned device memory
// (d_ws proved unsafe in round 1 — ws overrun corrupted pristine inputs).
//   W0f  [128x128] KT=4 NT=8  @ 0      (16384)
//   W1f  [128x64]  KT=4 NT=4  @ 16384  (8192)
//   Wvf  [64x128]  KT=2 NT=8  @ 24576  (8192)
//   We1f [64x128]  KT=2 NT=8  @ 32768  (8192)
//   W2f  [128x16]  KT=4 NT=1  @ 40960  (2048)
//   Wgf  [64x16]   KT=2 NT=1  @ 43008  (1024)
__device__ unsigned short g_Wf[44032];

__device__ __forceinline__ unsigned short f2bf(float f) {
    unsigned u = __builtin_bit_cast(unsigned, f);
    u += 0x7fffu + ((u >> 16) & 1u);   // RNE
    return (unsigned short)(u >> 16);
}

__device__ __forceinline__ unsigned pk2(float x, float y) {
    return (unsigned)f2bf(x) | ((unsigned)f2bf(y) << 16);
}

__device__ __forceinline__ sx8 cvt8(fx4 a, fx4 b) {
    ux4 u;
    u[0] = pk2(a[0], a[1]); u[1] = pk2(a[2], a[3]);
    u[2] = pk2(b[0], b[1]); u[3] = pk2(b[2], b[3]);
    return __builtin_bit_cast(sx8, u);
}

__device__ __forceinline__ float fast_tanh(float x) {
    x = fminf(15.f, fmaxf(-15.f, x));
    float t = __builtin_amdgcn_exp2f(x * 2.8853900817779268f); // e^(2x)
    return (t - 1.f) * __builtin_amdgcn_rcpf(t + 1.f);
}

__device__ __forceinline__ float fast_softplus(float x) {
    float xc = fminf(30.f, fmaxf(-30.f, x));
    float e = __builtin_amdgcn_exp2f(xc * 1.4426950408889634f);
    return 0.6931471805599453f * __builtin_amdgcn_logf(1.f + e);
}

// ---------------------------------------------------------------------------
// Unified weight packer: fp32 -> bf16 MFMA B-fragment layout into g_Wf.
// Lane l holds B[k = kt*32 + (l>>4)*8 + j][n = nt*16 + (l&15)], j=0..7.
// ---------------------------------------------------------------------------
__global__ void pack_all(const float* __restrict__ Ws0, const float* __restrict__ Ws1,
                         const float* __restrict__ Wv,  const float* __restrict__ wg,
                         const float* __restrict__ wn,  const float* __restrict__ We1,
                         const float* __restrict__ We2)
{
    int idx = blockIdx.x * 256 + threadIdx.x;   // grid covers exactly 44032
    int off, KT, mode, Ksrc = 0, Nsrc = 0;
    const float* src; const float* src2 = nullptr;
    if (idx < 16384)      { off = 0;     KT = 4; mode = 0; src = Ws0; Ksrc = 128; Nsrc = 128; }
    else if (idx < 24576) { off = 16384; KT = 4; mode = 0; src = Ws1; Ksrc = 128; Nsrc = 62;  }
    else if (idx < 32768) { off = 24576; KT = 2; mode = 0; src = Wv;  Ksrc = 62;  Nsrc = 128; }
    else if (idx < 40960) { off = 32768; KT = 2; mode = 1; src = We1; }
    else if (idx < 43008) { off = 40960; KT = 4; mode = 2; src = We2; }
    else                  { off = 43008; KT = 2; mode = 3; src = wg; src2 = wn; }

    int rel  = idx - off;
    int blk  = rel >> 9;
    int lane = (rel >> 3) & 63;
    int j    = rel & 7;
    int nt = blk / KT, kt = blk - nt * KT;
    int k = kt * 32 + (lane >> 4) * 8 + j;
    int n = nt * 16 + (lane & 15);
    float v = 0.f;
    if (mode == 0) {
        if (k < Ksrc && n < Nsrc) v = src[k * Nsrc + n];
    } else if (mode == 1) {              // We1[e][k][h] -> W[k][e*64+h]
        if (k < 62) { int e = n >> 6, h = n & 63; v = src[e * 3968 + k * 64 + h]; }
    } else if (mode == 2) {              // We2 block-diag
        int e = k >> 6; int c = n - e * 6;
        if ((unsigned)c < 6u) v = src[e * 384 + (k & 63) * 6 + c];
    } else {                             // gating: cols 0,1 = w_gate, 2,3 = w_noise
        if (k < 62) {
            if (n < 2) v = src[k * 2 + n];
            else if (n < 4) v = src2[k * 2 + (n - 2)];
        }
    }
    g_Wf[idx] = f2bf(v);
}

// ---------------------------------------------------------------------------
// Main fused kernel: 4 waves x 32 rows, WAVE-PRIVATE LDS, no __syncthreads.
// Each wave owns an 8704 B LDS slice; H(32x136 bf16), L(32x72 bf16),
// eh(32x136 bf16) and sS(32x21 f32) all overlay it — every tenant is fully
// consumed into registers before the next one's writes begin (within-wave
// LDS ops execute in order; WB() pins compiler ordering).
// LDS/block = 34816 B -> 4 blocks/CU (16 waves/CU) vs round-2's 2 blocks.
// ---------------------------------------------------------------------------
__global__ __launch_bounds__(256, 4)
void mlp_main(const float* __restrict__ X, const float* __restrict__ noise,
              const float* __restrict__ bs0, const float* __restrict__ bs1,
              const float* __restrict__ bv,  const float* __restrict__ be1,
              const float* __restrict__ be2, float* __restrict__ out)
{
    __shared__ __align__(16) unsigned short smem[4 * 4352];   // 4352 shorts = 8704 B per wave

    const int tid  = threadIdx.x;
    const int wave = tid >> 6;
    const int lane = tid & 63;
    const int lr   = lane & 15;   // A row / B col / C col
    const int lq   = lane >> 4;   // quad
    const int wr0  = blockIdx.x * 128 + wave * 32;   // this wave's first global row

    unsigned short* sW  = smem + wave * 4352;   // wave-private slice
    float*          sSf = (float*)sW;

    const unsigned short* W0f  = g_Wf;
    const unsigned short* W1f  = g_Wf + 16384;
    const unsigned short* Wvf  = g_Wf + 24576;
    const unsigned short* We1f = g_Wf + 32768;
    const unsigned short* W2f  = g_Wf + 40960;
    const unsigned short* Wgf  = g_Wf + 43008;

    float* out_act = out;                       // [B,6]
    float* out_vf  = out + (size_t)6 * BB;      // [B,128]
    float* out_eo  = out + (size_t)134 * BB;    // [B,12]

    // ---- Stage 1: H = tanh(X @ W0 + b0); A-frags straight from global fp32
    sx8 a[2][4];
    for (int m = 0; m < 2; m++) {
        const float* p = X + (size_t)(wr0 + m * 16 + lr) * 128 + lq * 8;
        for (int kt = 0; kt < 4; kt++) {
            fx4 u = *(const fx4*)(p + kt * 32);
            fx4 v = *(const fx4*)(p + kt * 32 + 4);
            a[m][kt] = cvt8(u, v);
        }
    }
    for (int nt = 0; nt < 8; nt++) {
        sx8 b[4];
        for (int kt = 0; kt < 4; kt++)
            b[kt] = *(const sx8*)(W0f + (((nt * 4 + kt) * 64 + lane) << 3));
        int col = nt * 16 + lr;
        float bias = bs0[col];
        for (int m = 0; m < 2; m++) {
            fx4 acc = {0.f, 0.f, 0.f, 0.f};
            for (int kt = 0; kt < 4; kt++)
                acc = __builtin_amdgcn_mfma_f32_16x16x32_bf16(a[m][kt], b[kt], acc, 0, 0, 0);
            unsigned short* dst = sW + (m * 16 + lq * 4) * 136 + col;
            for (int r = 0; r < 4; r++)
                dst[r * 136] = f2bf(fast_tanh(acc[r] + bias));
        }
    }
    WB();

    // ---- Stage 2: L = tanh(H @ W1 + b1); H fully loaded to regs, then L overlays
    for (int m = 0; m < 2; m++)
        for (int kt = 0; kt < 4; kt++)
            a[m][kt] = *(const sx8*)(sW + (m * 16 + lr) * 136 + kt * 32 + lq * 8);
    WB();
    for (int nt = 0; nt < 4; nt++) {
        sx8 b[4];
        for (int kt = 0; kt < 4; kt++)
            b[kt] = *(const sx8*)(W1f + (((nt * 4 + kt) * 64 + lane) << 3));
        int col = nt * 16 + lr;
        float bias = (col < 62) ? bs1[col] : 0.f;
        for (int m = 0; m < 2; m++) {
            fx4 acc = {0.f, 0.f, 0.f, 0.f};
            for (int kt = 0; kt < 4; kt++)
                acc = __builtin_amdgcn_mfma_f32_16x16x32_bf16(a[m][kt], b[kt], acc, 0, 0, 0);
            unsigned short* dst = sW + (m * 16 + lq * 4) * 72 + col;   // L: stride 72
            for (int r = 0; r < 4; r++)
                dst[r * 72] = f2bf(fast_tanh(acc[r] + bias));
        }
    }
    WB();

    // ---- Stage 3a: eh = relu(L @ We1c + be1c); L loaded to regs, eh overlays
    sx8 aL[2][2];
    for (int m = 0; m < 2; m++)
        for (int kt = 0; kt < 2; kt++)
            aL[m][kt] = *(const sx8*)(sW + (m * 16 + lr) * 72 + kt * 32 + lq * 8);
    WB();
    for (int nt = 0; nt < 8; nt++) {
        sx8 b0 = *(const sx8*)(We1f + (((nt * 2 + 0) * 64 + lane) << 3));
        sx8 b1 = *(const sx8*)(We1f + (((nt * 2 + 1) * 64 + lane) << 3));
        int col = nt * 16 + lr;
        float bias = be1[col];   // be1 flat [2,64] == combined [128]
        for (int m = 0; m < 2; m++) {
            fx4 acc = {0.f, 0.f, 0.f, 0.f};
            acc = __builtin_amdgcn_mfma_f32_16x16x32_bf16(aL[m][0], b0, acc, 0, 0, 0);
            acc = __builtin_amdgcn_mfma_f32_16x16x32_bf16(aL[m][1], b1, acc, 0, 0, 0);
            unsigned short* dst = sW + (m * 16 + lq * 4) * 136 + col;  // eh: stride 136
            for (int r = 0; r < 4; r++)
                dst[r * 136] = f2bf(fmaxf(acc[r] + bias, 0.f));
        }
    }
    // ---- Stage 3b: latent_vf = tanh(L @ Wv + bv) -> global (uses aL regs only)
    for (int nt = 0; nt < 8; nt++) {
        sx8 b0 = *(const sx8*)(Wvf + (((nt * 2 + 0) * 64 + lane) << 3));
        sx8 b1 = *(const sx8*)(Wvf + (((nt * 2 + 1) * 64 + lane) << 3));
        int col = nt * 16 + lr;
        float bias = bv[col];
        for (int m = 0; m < 2; m++) {
            fx4 acc = {0.f, 0.f, 0.f, 0.f};
            acc = __builtin_amdgcn_mfma_f32_16x16x32_bf16(aL[m][0], b0, acc, 0, 0, 0);
            acc = __builtin_amdgcn_mfma_f32_16x16x32_bf16(aL[m][1], b1, acc, 0, 0, 0);
            float* dst = out_vf + (size_t)(wr0 + m * 16 + lq * 4) * 128 + col;
            for (int r = 0; r < 4; r++)
                dst[(size_t)r * 128] = fast_tanh(acc[r] + bias);
        }
    }
    WB();

    // ---- Stage 4a: expert logits = eh @ W2bd; eh loaded to regs, sS overlays
    sx8 ae[2][4];
    for (int m = 0; m < 2; m++)
        for (int kt = 0; kt < 4; kt++)
            ae[m][kt] = *(const sx8*)(sW + (m * 16 + lr) * 136 + kt * 32 + lq * 8);
    WB();
    {
        sx8 bw[4];
        for (int kt = 0; kt < 4; kt++)
            bw[kt] = *(const sx8*)(W2f + ((kt * 64 + lane) << 3));
        for (int m = 0; m < 2; m++) {
            fx4 acc = {0.f, 0.f, 0.f, 0.f};
            for (int kt = 0; kt < 4; kt++)
                acc = __builtin_amdgcn_mfma_f32_16x16x32_bf16(ae[m][kt], bw[kt], acc, 0, 0, 0);
            float* dst = sSf + (m * 16 + lq * 4) * 21 + lr;
            for (int r = 0; r < 4; r++) dst[r * 21] = acc[r];
        }
    }
    // ---- Stage 4b: gating logits = L @ [wg|wn] -> sS cols 16..19 (aL regs)
    {
        sx8 bg0 = *(const sx8*)(Wgf + ((0 * 64 + lane) << 3));
        sx8 bg1 = *(const sx8*)(Wgf + ((1 * 64 + lane) << 3));
        for (int m = 0; m < 2; m++) {
            fx4 acc = {0.f, 0.f, 0.f, 0.f};
            acc = __builtin_amdgcn_mfma_f32_16x16x32_bf16(aL[m][0], bg0, acc, 0, 0, 0);
            acc = __builtin_amdgcn_mfma_f32_16x16x32_bf16(aL[m][1], bg1, acc, 0, 0, 0);
            if (lr < 4) {
                float* dst = sSf + (m * 16 + lq * 4) * 21 + 16 + lr;
                for (int r = 0; r < 4; r++) dst[r * 21] = acc[r];
            }
        }
    }
    WB();

    // ---- Epilogue: lanes 0..31 each finish one of this wave's 32 rows
    if (lane < 32) {
        const float* Srow = sSf + lane * 21;
        int grow = wr0 + lane;
        fx2 nz = *(const fx2*)(noise + (size_t)grow * 2);
        float sp0 = fast_softplus(Srow[18]) + 1e-2f;
        float sp1 = fast_softplus(Srow[19]) + 1e-2f;
        float l0 = Srow[16] + nz[0] * sp0;
        float l1 = Srow[17] + nz[1] * sp1;
        float mg = fmaxf(l0, l1);
        float e0 = __builtin_amdgcn_exp2f((l0 - mg) * 1.4426950408889634f);
        float e1 = __builtin_amdgcn_exp2f((l1 - mg) * 1.4426950408889634f);
        float gi = __builtin_amdgcn_rcpf(e0 + e1);
        float g0 = e0 * gi, g1 = e1 * gi;

        float eo[12];
        for (int e = 0; e < 2; e++) {
            float lg[6]; float mx = -1e30f;
            for (int c = 0; c < 6; c++) {
                lg[c] = Srow[e * 6 + c] + be2[e * 6 + c];
                mx = fmaxf(mx, lg[c]);
            }
            float s = 0.f;
            for (int c = 0; c < 6; c++) {
                lg[c] = __builtin_amdgcn_exp2f((lg[c] - mx) * 1.4426950408889634f);
                s += lg[c];
            }
            float inv = __builtin_amdgcn_rcpf(s);
            for (int c = 0; c < 6; c++) eo[e * 6 + c] = lg[c] * inv;
        }
        float* pe = out_eo + (size_t)grow * 12;
        for (int c = 0; c < 3; c++)
            ((fx4*)pe)[c] = *(const fx4*)(eo + 4 * c);
        float* pa = out_act + (size_t)grow * 6;
        for (int c = 0; c < 6; c += 2) {
            fx2 v; v[0] = g0 * eo[c] + g1 * eo[6 + c];
            v[1] = g0 * eo[c + 1] + g1 * eo[7 + c];
            *(fx2*)(pa + c) = v;
        }
    }
}

extern "C" void kernel_launch(void* const* d_in, const int* in_sizes, int n_in,
                              void* d_out, int out_size, void* d_ws, size_t ws_size,
                              hipStream_t stream)
{
    const float* X    = (const float*)d_in[0];
    const float* nz   = (const float*)d_in[1];
    const float* Ws0  = (const float*)d_in[2];
    const float* bs0  = (const float*)d_in[3];
    const float* Ws1  = (const float*)d_in[4];
    const float* bs1  = (const float*)d_in[5];
    const float* Wv   = (const float*)d_in[6];
    const float* bv   = (const float*)d_in[7];
    const float* wg   = (const float*)d_in[8];
    const float* wn   = (const float*)d_in[9];
    const float* We1  = (const float*)d_in[10];
    const float* be1  = (const float*)d_in[11];
    const float* We2  = (const float*)d_in[12];
    const float* be2  = (const float*)d_in[13];

    pack_all<<<172, 256, 0, stream>>>(Ws0, Ws1, Wv, wg, wn, We1, We2);
    mlp_main<<<BB / 128, 256, 0, stream>>>(X, nz, bs0, bs1, bv, be1, be2, (float*)d_out);
}